// Round 19
// baseline (544.798 us; speedup 1.0000x reference)
//
#include <hip/hip_runtime.h>
#include <hip/hip_bf16.h>
#include <math.h>

#define HH 192
#define WW 192
#define WF 97
#define NC 8
#define NC2 16
#define NT 32
#define NB 2
#define NIMG (NB*NT)        // 64
#define NPLANE (NIMG*NC)    // 512
#define PIX (HH*WW)         // 36864
#define FPIX (HH*WF)        // 18624  (layout: [plane][kx][ky], f = kx*192+ky)
#define HP (FPIX/2)         // 9312
#define NG 13               // kx groups of 8 (8*12+1 = 97)
#define INV_SQRT_N 0.07216878364870322f   // 1/sqrt(192)
#define SCAN_BLOCKS (NB*NC*HP/256)        // 582; b never straddles a block
#define NBI (NIMG*100)      // interior force blocks
#define NBB (NIMG*44)       // border force blocks

typedef __attribute__((ext_vector_type(8))) short bf16x8;
typedef __attribute__((ext_vector_type(4))) float f32x4;

__device__ inline unsigned short f2bf(float f){
    union { __hip_bfloat16 h; unsigned short u; } cv;
    cv.h = __float2bfloat16(f);          // HW cvt; compiler packs pairs
    return cv.u;
}
__device__ inline float bf2f(unsigned short h){
    return __uint_as_float(((unsigned int)h) << 16);
}
__device__ inline float fsigmoid(float y){
    return __builtin_amdgcn_rcpf(1.f + __expf(-y));   // 4 VALU instrs
}

// ---- per-thread FFT twiddle table: twt[(dir*28+s)*192 + t] (lane-coalesced)
__global__ void k_twt(float2* __restrict__ twt){
    int e = blockIdx.x*256 + threadIdx.x;        // 2*28*192 = 10752
    if (e >= 10752) return;
    int t = e % 192; int s = (e/192) % 28; int d = e / (192*28);
    int m;
    if (s < 16){ int k1 = t/12, n2 = t%12; m = (n2*k1 + 12*k1*s) % 192; }
    else       { int q = s - 16; int k2 = t/16; m = (16*k2*q) % 192; }
    double ang = 6.283185307179586476925286766559 * (double)m / 192.0;
    float cn = (float)cos(ang), sn = (float)sin(ang);
    float2 w; w.x = cn; w.y = d ? sn : -sn;
    twt[(d*28 + s)*192 + t] = w;
}

// ------- weight fragment table: exact per-lane MFMA A-layout, bf16 -------
__global__ void k_wprep(const float* __restrict__ c1w, const float* __restrict__ c2w,
                        const float* __restrict__ c3w,
                        unsigned short* __restrict__ WT, float* __restrict__ S3){
    int e = blockIdx.x*256 + threadIdx.x;
    if (e < 9216){
        int j  = e & 7;
        int l  = (e >> 3) & 63;
        int fs = e >> 9;
        int px = l & 15, ks = l >> 4;
        float w = 0.f;
        if (fs < 3){                         // ph1: conv1 fwd, K=4taps x 8ch
            int tap = 4*fs + ks;
            if (tap < 9) w = c1w[(px*8 + j)*9 + tap];
        } else if (fs < 8){                  // ph2: conv2 fwd, K=2taps x 16ch
            int s = fs - 3, tap = 2*s + (ks>>1);
            int ch = (ks&1)*8 + j;
            if (tap < 9) w = c2w[(px*16 + ch)*9 + tap];
        } else if (fs < 13){                 // ph3: conv2^T (flipped taps)
            int s = fs - 8, tb = 2*s + (ks>>1);
            int c2 = (ks&1)*8 + j;
            if (tb < 9) w = c2w[(c2*16 + px)*9 + (8 - tb)];
        } else {                             // ph4: conv1^T
            int s = fs - 13, tb = 2*s + (ks>>1);
            int cin = (ks&1)*8 + j;
            if (tb < 9 && px < 8) w = c1w[(cin*8 + px)*9 + (8 - tb)];
        }
        WT[e] = f2bf(w);
    } else if (e < 9232){
        int och = e - 9216;
        float s3 = 0.f;
        for (int q = 0; q < NC; q++) s3 += c3w[q*NC2 + och];
        S3[och] = s3;
    }
}

// ---------------- A = exp(i*omega*dt) via MLP (f = kx*192+ky) ----------------
__global__ void k_A(const float* __restrict__ dt, const float* __restrict__ w1,
                    const float* __restrict__ b1, const float* __restrict__ w2,
                    const float* __restrict__ b2, float* __restrict__ Abuf){
    int idx = blockIdx.x*blockDim.x + threadIdx.x;
    if (idx >= FPIX) return;
    int kyi = idx % HH, kxi = idx / HH;
    float ky = (float)(kyi < 96 ? kyi : kyi - 192) / 192.0f;
    float kx = (float)kxi / 192.0f;
    float lp[NC];
    #pragma unroll
    for (int c = 0; c < NC; c++) lp[c] = b2[c];
    for (int jh = 0; jh < 64; jh++){
        float z  = ky*w1[jh] + kx*w1[64+jh] + b1[jh];
        float sg = __builtin_amdgcn_rcpf(1.0f + __expf(-z));
        float h  = z*sg;
        #pragma unroll
        for (int c = 0; c < NC; c++) lp[c] += h * w2[jh*NC + c];
    }
    float kph = sqrtf(ky*ky + kx*kx);
    for (int b = 0; b < NB; b++){
        float d = dt[b];
        #pragma unroll
        for (int c = 0; c < NC; c++){
            float ph = (lp[c] + kph) * d;
            float s, cn;
            __sincosf(ph, &s, &cn);
            long o = (((long)(b*NC + c))*FPIX + idx) * 2;
            Abuf[o]   = cn;
            Abuf[o+1] = s;
        }
    }
}

// ============ FUSED force chain body (interior/border specialized) ========
template<int BORDER>
__device__ __forceinline__ void force_body(
        int img, int tx0, int ty0,
        const float* __restrict__ x, const bf16x8* __restrict__ wt,
        const float* __restrict__ c1b, const float* __restrict__ c2b,
        const float* __restrict__ S3,  const float* __restrict__ dt,
        float* __restrict__ xp,
        unsigned short* ys1_s, unsigned short* xg2_s){
    int tid = threadIdx.x;
    int l = tid & 63, px = l & 15, ks = l >> 4, wv = tid >> 6;

    // ---- stage x: 24x24 halo, 8ch ch-last bf16 ----
    unsigned short* xs = xg2_s;                  // [pix*8 + c]
    const float* xb = x + (long)img*NC*PIX;
    for (int pix = tid; pix < 576; pix += 256){
        int sy = pix / 24, sx = pix % 24;
        int gy = ty0 - 4 + sy, gx = tx0 - 4 + sx;
        bool vld = true;
        if constexpr (BORDER != 0)
            vld = (gy >= 0 && gy < HH && gx >= 0 && gx < WW);
        long gp = (long)gy*WW + gx;
        ushort4 o0, o1;
        #pragma unroll
        for (int c = 0; c < 8; c++){
            float v = vld ? xb[c*PIX + gp] : 0.f;
            unsigned short h = f2bf(v);
            if (c < 4) ((unsigned short*)&o0)[c] = h;
            else       ((unsigned short*)&o1)[c-4] = h;
        }
        *(ushort4*)(xs + pix*8)     = o0;
        *(ushort4*)(xs + pix*8 + 4) = o1;
    }
    __syncthreads();

    ushort4 dy1r[6];                             // dy1 inner tile, in regs
    // ---- phase 1: conv1 -> ys1 (22x22x16), dy1 (18x18) in registers ----
    {
        bf16x8 a0 = wt[0*64 + l], a1 = wt[1*64 + l], a2 = wt[2*64 + l];
        float b1v[4];
        #pragma unroll
        for (int r = 0; r < 4; r++) b1v[r] = c1b[ks*4 + r];
        int t0 = (0 + ks < 9) ? ks : 8;          // taps for s=0,1,2
        int t1 = (4 + ks < 9) ? 4 + ks : 8;
        int t2 = 8;
        int o0 = ((t0/3)*24 + t0%3)*8, o1 = ((t1/3)*24 + t1%3)*8, o2 = ((t2/3)*24 + t2%3)*8;
        // pass A: inner 324 pixels (18x18), SAME p-mapping as phase 3
        #pragma unroll
        for (int i = 0; i < 6; i++){
            int g = wv + 4*i;
            if (g < 21){
                int p = g*16 + px;
                int pc = (p < 324) ? p : 323;
                int ry = pc/18, rx = pc%18;
                const unsigned short* bp = xs + ((ry+2)*24 + rx+2)*8;
                f32x4 acc = {0.f,0.f,0.f,0.f};
                acc = __builtin_amdgcn_mfma_f32_16x16x32_bf16(a0, *(const bf16x8*)(bp+o0), acc, 0,0,0);
                acc = __builtin_amdgcn_mfma_f32_16x16x32_bf16(a1, *(const bf16x8*)(bp+o1), acc, 0,0,0);
                acc = __builtin_amdgcn_mfma_f32_16x16x32_bf16(a2, *(const bf16x8*)(bp+o2), acc, 0,0,0);
                bool vld = true;
                if constexpr (BORDER != 0){
                    int gy = ty0 - 1 + ry, gx = tx0 - 1 + rx;
                    vld = (gy >= 0 && gy < HH && gx >= 0 && gx < WW);
                }
                ushort4 yo, dyo;
                #pragma unroll
                for (int r = 0; r < 4; r++){
                    float yv = acc[r] + b1v[r];
                    float sg = fsigmoid(yv);
                    ((unsigned short*)&yo)[r]  = vld ? f2bf(yv*sg) : (unsigned short)0;
                    ((unsigned short*)&dyo)[r] = vld ? f2bf(sg*(1.f + yv*(1.f - sg)))
                                                     : (unsigned short)0;
                }
                dy1r[i] = dyo;
                if (p < 324)
                    *(ushort4*)(ys1_s + ((ry+2)*22 + rx+2)*16 + ks*4) = yo;
            }
        }
        // pass B: ring 160 pixels of the 22x22 ys1 tile (no dy1 needed)
        #pragma unroll
        for (int i = 0; i < 3; i++){
            int g = wv + 4*i;
            if (g < 10){
                int p = g*16 + px;               // 0..159
                int oy, ox;
                if (p < 88){ int q = p/22; oy = (q < 2) ? q : q + 18; ox = p - q*22; }
                else { int rr = p - 88; oy = (rr>>2) + 2; int c4 = rr & 3;
                       ox = (c4 < 2) ? c4 : c4 + 18; }
                const unsigned short* bp = xs + (oy*24 + ox)*8;
                f32x4 acc = {0.f,0.f,0.f,0.f};
                acc = __builtin_amdgcn_mfma_f32_16x16x32_bf16(a0, *(const bf16x8*)(bp+o0), acc, 0,0,0);
                acc = __builtin_amdgcn_mfma_f32_16x16x32_bf16(a1, *(const bf16x8*)(bp+o1), acc, 0,0,0);
                acc = __builtin_amdgcn_mfma_f32_16x16x32_bf16(a2, *(const bf16x8*)(bp+o2), acc, 0,0,0);
                bool vld = true;
                if constexpr (BORDER != 0){
                    int gy = ty0 - 3 + oy, gx = tx0 - 3 + ox;
                    vld = (gy >= 0 && gy < HH && gx >= 0 && gx < WW);
                }
                ushort4 yo;
                #pragma unroll
                for (int r = 0; r < 4; r++){
                    float yv = acc[r] + b1v[r];
                    float sg = fsigmoid(yv);
                    ((unsigned short*)&yo)[r] = vld ? f2bf(yv*sg) : (unsigned short)0;
                }
                *(ushort4*)(ys1_s + (oy*22 + ox)*16 + ks*4) = yo;
            }
        }
    }
    __syncthreads();

    // ---- phase 2: conv2 -> g2 (20x20x16) over dead xs ----
    unsigned short* g2s = xg2_s;
    {
        bf16x8 a0 = wt[3*64+l], a1 = wt[4*64+l], a2 = wt[5*64+l],
               a3 = wt[6*64+l], a4 = wt[7*64+l];
        float b2v[4], s3v[4];
        #pragma unroll
        for (int r = 0; r < 4; r++){ b2v[r] = c2b[ks*4+r]; s3v[r] = S3[ks*4+r]; }
        int hb = (ks&1)*8;
        int toff[5];
        #pragma unroll
        for (int s = 0; s < 5; s++){
            int tap = 2*s + (ks>>1); int t = (tap < 9) ? tap : 8;
            toff[s] = ((t/3)*22 + t%3)*16 + hb;
        }
        #pragma unroll
        for (int i = 0; i < 7; i++){
            int g = wv + 4*i;
            if (g < 25){
                int p = g*16 + px;               // < 400 always
                int qy = p/20, qx = p%20;
                const unsigned short* bp = ys1_s + (qy*22 + qx)*16;
                f32x4 acc = {0.f,0.f,0.f,0.f};
                acc = __builtin_amdgcn_mfma_f32_16x16x32_bf16(a0, *(const bf16x8*)(bp+toff[0]), acc, 0,0,0);
                acc = __builtin_amdgcn_mfma_f32_16x16x32_bf16(a1, *(const bf16x8*)(bp+toff[1]), acc, 0,0,0);
                acc = __builtin_amdgcn_mfma_f32_16x16x32_bf16(a2, *(const bf16x8*)(bp+toff[2]), acc, 0,0,0);
                acc = __builtin_amdgcn_mfma_f32_16x16x32_bf16(a3, *(const bf16x8*)(bp+toff[3]), acc, 0,0,0);
                acc = __builtin_amdgcn_mfma_f32_16x16x32_bf16(a4, *(const bf16x8*)(bp+toff[4]), acc, 0,0,0);
                bool vld = true;
                if constexpr (BORDER != 0){
                    int gy = ty0 - 2 + qy, gx = tx0 - 2 + qx;
                    vld = (gy >= 0 && gy < HH && gx >= 0 && gx < WW);
                }
                ushort4 go;
                #pragma unroll
                for (int r = 0; r < 4; r++){
                    float yv = acc[r] + b2v[r];
                    float sg = fsigmoid(yv);
                    float ds = sg*(1.f + yv*(1.f - sg));
                    ((unsigned short*)&go)[r] = vld ? f2bf(ds * s3v[r]) : (unsigned short)0;
                }
                *(ushort4*)(g2s + p*16 + ks*4) = go;
            }
        }
    }
    __syncthreads();

    // ---- phase 3: g1 = dy1r * conv2^T(g2) (18x18x16) over dead ys1 ----
    unsigned short* g1s = ys1_s;
    {
        bf16x8 a0 = wt[8*64+l], a1 = wt[9*64+l], a2 = wt[10*64+l],
               a3 = wt[11*64+l], a4 = wt[12*64+l];
        int hb = (ks&1)*8;
        int toff[5];
        #pragma unroll
        for (int s = 0; s < 5; s++){
            int tb = 2*s + (ks>>1); int t = (tb < 9) ? tb : 8;
            toff[s] = ((2-(t/3))*20 + 2-(t%3))*16 + hb;   // flipped taps
        }
        #pragma unroll
        for (int i = 0; i < 6; i++){
            int g = wv + 4*i;
            if (g < 21){
                int p = g*16 + px;
                int pc = (p < 324) ? p : 323;
                int ry = pc/18, rx = pc%18;
                const unsigned short* bp = g2s + (ry*20 + rx)*16;
                f32x4 acc = {0.f,0.f,0.f,0.f};
                acc = __builtin_amdgcn_mfma_f32_16x16x32_bf16(a0, *(const bf16x8*)(bp+toff[0]), acc, 0,0,0);
                acc = __builtin_amdgcn_mfma_f32_16x16x32_bf16(a1, *(const bf16x8*)(bp+toff[1]), acc, 0,0,0);
                acc = __builtin_amdgcn_mfma_f32_16x16x32_bf16(a2, *(const bf16x8*)(bp+toff[2]), acc, 0,0,0);
                acc = __builtin_amdgcn_mfma_f32_16x16x32_bf16(a3, *(const bf16x8*)(bp+toff[3]), acc, 0,0,0);
                acc = __builtin_amdgcn_mfma_f32_16x16x32_bf16(a4, *(const bf16x8*)(bp+toff[4]), acc, 0,0,0);
                if (p < 324){
                    ushort4 dv = dy1r[i];
                    ushort4 go;
                    #pragma unroll
                    for (int r = 0; r < 4; r++){
                        float v = acc[r] * bf2f(((unsigned short*)&dv)[r]);
                        ((unsigned short*)&go)[r] = f2bf(v);
                    }
                    *(ushort4*)(g1s + p*16 + ks*4) = go;
                }
            }
        }
    }
    __syncthreads();

    // ---- phase 4: xp = x + dt * conv1^T(g1), 16x16, 8 out-ch ----
    {
        bf16x8 a0 = wt[13*64+l], a1 = wt[14*64+l], a2 = wt[15*64+l],
               a3 = wt[16*64+l], a4 = wt[17*64+l];
        int hb = (ks&1)*8;
        int toff[5];
        #pragma unroll
        for (int s = 0; s < 5; s++){
            int tb = 2*s + (ks>>1); int t = (tb < 9) ? tb : 8;
            toff[s] = ((2-(t/3))*18 + 2-(t%3))*16 + hb;
        }
        float d = dt[img / NT];
        #pragma unroll
        for (int i = 0; i < 4; i++){
            int y = wv + 4*i;
            const unsigned short* bp = g1s + (y*18 + px)*16;
            f32x4 acc = {0.f,0.f,0.f,0.f};
            acc = __builtin_amdgcn_mfma_f32_16x16x32_bf16(a0, *(const bf16x8*)(bp+toff[0]), acc, 0,0,0);
            acc = __builtin_amdgcn_mfma_f32_16x16x32_bf16(a1, *(const bf16x8*)(bp+toff[1]), acc, 0,0,0);
            acc = __builtin_amdgcn_mfma_f32_16x16x32_bf16(a2, *(const bf16x8*)(bp+toff[2]), acc, 0,0,0);
            acc = __builtin_amdgcn_mfma_f32_16x16x32_bf16(a3, *(const bf16x8*)(bp+toff[3]), acc, 0,0,0);
            acc = __builtin_amdgcn_mfma_f32_16x16x32_bf16(a4, *(const bf16x8*)(bp+toff[4]), acc, 0,0,0);
            if (ks < 2){
                int gpix = (ty0+y)*WW + (tx0+px);
                #pragma unroll
                for (int r = 0; r < 4; r++){
                    int c = ks*4 + r;
                    long gi = ((long)img*NC + c)*PIX + gpix;
                    xp[gi] = x[gi] + d*acc[r];
                }
            }
        }
    }
}

// single launch: interior blocks [0, NBI), border blocks [NBI, NBI+NBB)
__global__ void __launch_bounds__(256) k_force_all(
        const float* __restrict__ x, const unsigned short* __restrict__ WTu,
        const float* __restrict__ c1b, const float* __restrict__ c2b,
        const float* __restrict__ S3,  const float* __restrict__ dt,
        float* __restrict__ xp){
    __shared__ unsigned short ys1_s[22*22*16];   // later g1 (18x18x16)
    __shared__ unsigned short xg2_s[20*20*16];   // xs (24x24x8) then g2
    const bf16x8* wt = (const bf16x8*)WTu;
    int bid = blockIdx.x;
    if (bid < NBI){
        int img = bid / 100; int t10 = bid % 100;
        int ty0 = (1 + t10/10)*16, tx0 = (1 + t10%10)*16;
        force_body<0>(img, tx0, ty0, x, wt, c1b, c2b, S3, dt, xp, ys1_s, xg2_s);
    } else {
        int e0 = bid - NBI;
        int img = e0 / 44; int e = e0 % 44;
        int r, c;
        if (e < 12){ r = 0; c = e; }
        else if (e < 24){ r = 11; c = e - 12; }
        else if (e < 34){ r = e - 23; c = 0; }
        else { r = e - 33; c = 11; }
        force_body<1>(img, c*16, r*16, x, wt, c1b, c2b, S3, dt, xp, ys1_s, xg2_s);
    }
}

// ====== row rfft (192=16x12), 384 threads: 2 threads per output point =====
// (16-row tiling + all LDS/global access patterns preserved; only the
//  per-point reduction is split across thread pairs, combined via shfl_xor)
__global__ void k_rowfft2(const float* __restrict__ xp, const float2* __restrict__ twt,
                          float* __restrict__ R){
    __shared__ float2 bufC[1728];
    __shared__ float2 bufA[1836];
    int p  = blockIdx.x / 12;
    int r0 = (blockIdx.x % 12)*16;
    int t  = threadIdx.x;                        // 0..383
    {   // load: t<192 -> jj 0..3, t>=192 -> jj 4..7
        int u2 = t % 192, hf = t / 192;
        const float* base = xp + (long)p*PIX + (long)r0*WW;
        #pragma unroll
        for (int j2 = 0; j2 < 4; j2++){
            int jj = hf*4 + j2;
            float2 z; z.x = base[(2*jj)*WW + u2]; z.y = base[(2*jj+1)*WW + u2];
            bufC[u2*9 + jj] = z;
        }
    }
    __syncthreads();
    int u = t >> 1, h = t & 1;
    {   // stage 1 (fwd): pair splits n1 0-7 / 8-15
        int n2 = u % 12;
        float wr[8], wi[8];
        #pragma unroll
        for (int n = 0; n < 8; n++){
            float2 w = twt[(8*h + n)*192 + u];
            wr[n] = w.x; wi[n] = w.y;
        }
        int k1 = u / 12;
        #pragma unroll
        for (int jj = 0; jj < 8; jj++){
            float re = 0.f, im = 0.f;
            #pragma unroll
            for (int n = 0; n < 8; n++){
                float2 v = bufC[(12*(8*h + n) + n2)*9 + jj];
                re += v.x*wr[n] - v.y*wi[n];
                im += v.x*wi[n] + v.y*wr[n];
            }
            float reT = re + __shfl_xor(re, 1);
            float imT = im + __shfl_xor(im, 1);
            if (h == 0){
                float2 a; a.x = reT; a.y = imT;
                bufA[(n2*17 + k1)*9 + jj] = a;
            }
        }
    }
    __syncthreads();
    {   // stage 2: pair splits q 0-5 / 6-11
        int kk1 = u % 16;
        float wr[6], wi[6];
        #pragma unroll
        for (int q = 0; q < 6; q++){
            float2 w = twt[(16 + 6*h + q)*192 + u];
            wr[q] = w.x; wi[q] = w.y;
        }
        #pragma unroll
        for (int jj = 0; jj < 8; jj++){
            float re = 0.f, im = 0.f;
            #pragma unroll
            for (int q = 0; q < 6; q++){
                float2 a = bufA[((6*h + q)*17 + kk1)*9 + jj];
                re += a.x*wr[q] - a.y*wi[q];
                im += a.x*wi[q] + a.y*wr[q];
            }
            float reT = re + __shfl_xor(re, 1);
            float imT = im + __shfl_xor(im, 1);
            if (h == 0){
                float2 z; z.x = reT*INV_SQRT_N; z.y = imT*INV_SQRT_N;
                bufC[u*9 + jj] = z;
            }
        }
    }
    __syncthreads();
    if (t < WF){   // Hermitian unpack -> U (overlaid on bufA)
        int t2 = (t == 0) ? 0 : 192 - t;
        #pragma unroll
        for (int jj = 0; jj < 8; jj++){
            float2 uu = bufC[t*9 + jj], v = bufC[t2*9 + jj];
            float2 A_; A_.x = 0.5f*(uu.x + v.x); A_.y = 0.5f*(uu.y - v.y);
            float2 B_; B_.x = 0.5f*(uu.y + v.y); B_.y = -0.5f*(uu.x - v.x);
            bufA[t*17 + 2*jj]     = A_;
            bufA[t*17 + 2*jj + 1] = B_;
        }
    }
    __syncthreads();
    float2* dst = ((float2*)R) + (long)p*FPIX + r0;
    for (int idx = t; idx < 97*16; idx += 384){
        int kx = idx >> 4, ry = idx & 15;
        dst[(long)kx*HH + ry] = bufA[kx*17 + ry];
    }
}

// ====== inverse row irfft, 384 threads; in [plane][kx][ky] ==============
// C2R: Im of DC (kx=0) and Nyquist (kx=96) bins zeroed (numpy convention).
__global__ void k_invrow2(const float* __restrict__ G, const float2* __restrict__ twt,
                          float* __restrict__ out){
    __shared__ float2 bufC[1728];
    __shared__ float2 bufA[1836];
    int p  = blockIdx.x / 12;
    int r0 = (blockIdx.x % 12)*16;
    int t  = threadIdx.x;                        // 0..383
    const float2* Gb = ((const float2*)G) + (long)p*FPIX + r0;
    for (int idx = t; idx < 97*16; idx += 384){
        int kx = idx >> 4, ry = idx & 15;
        bufA[kx*17 + ry] = Gb[(long)kx*HH + ry];
    }
    __syncthreads();
    {   // z-construction: t<192 -> jj 0..3, t>=192 -> jj 4..7
        int u2 = t % 192, hf = t / 192;
        int tt = (u2 <= 96) ? u2 : 192 - u2;
        bool dcny = (u2 == 0) || (u2 == 96);
        #pragma unroll
        for (int j2 = 0; j2 < 4; j2++){
            int jj = hf*4 + j2;
            float2 a = bufA[tt*17 + 2*jj];
            float2 b = bufA[tt*17 + 2*jj + 1];
            if (dcny){ a.y = 0.f; b.y = 0.f; }
            float2 z;
            if (u2 <= 96){ z.x = a.x - b.y; z.y = a.y + b.x; }
            else         { z.x = a.x + b.y; z.y = b.x - a.y; }
            bufC[u2*9 + jj] = z;
        }
    }
    __syncthreads();
    int u = t >> 1, h = t & 1;
    const float2* T = twt + 28*192;              // dir 1 (inverse)
    {   // stage 1 (e^{+i})
        int n2 = u % 12;
        float wr[8], wi[8];
        #pragma unroll
        for (int n = 0; n < 8; n++){
            float2 w = T[(8*h + n)*192 + u];
            wr[n] = w.x; wi[n] = w.y;
        }
        int k1 = u / 12;
        #pragma unroll
        for (int jj = 0; jj < 8; jj++){
            float re = 0.f, im = 0.f;
            #pragma unroll
            for (int n = 0; n < 8; n++){
                float2 v = bufC[(12*(8*h + n) + n2)*9 + jj];
                re += v.x*wr[n] - v.y*wi[n];
                im += v.x*wi[n] + v.y*wr[n];
            }
            float reT = re + __shfl_xor(re, 1);
            float imT = im + __shfl_xor(im, 1);
            if (h == 0){
                float2 a; a.x = reT; a.y = imT;
                bufA[(n2*17 + k1)*9 + jj] = a;
            }
        }
    }
    __syncthreads();
    {   // stage 2 (e^{+i}): Re->rowA, Im->rowB, straight to global
        int kk1 = u % 16;
        float wr[6], wi[6];
        #pragma unroll
        for (int q = 0; q < 6; q++){
            float2 w = T[(16 + 6*h + q)*192 + u];
            wr[q] = w.x; wi[q] = w.y;
        }
        float* ob = out + (long)p*PIX + (long)r0*WW;
        #pragma unroll
        for (int jj = 0; jj < 8; jj++){
            float re = 0.f, im = 0.f;
            #pragma unroll
            for (int q = 0; q < 6; q++){
                float2 a = bufA[((6*h + q)*17 + kk1)*9 + jj];
                re += a.x*wr[q] - a.y*wi[q];
                im += a.x*wi[q] + a.y*wr[q];
            }
            float reT = re + __shfl_xor(re, 1);
            float imT = im + __shfl_xor(im, 1);
            if (h == 0){
                ob[(2*jj)*WW + u]   = reT*INV_SQRT_N;
                ob[(2*jj+1)*WW + u] = imT*INV_SQRT_N;
            }
        }
    }
}

// ========== column FFT on [plane][kx][ky], 384 threads ===============
template<int DIRSGN, bool RESCALE>
__global__ void k_cfft(const float* __restrict__ in, const float2* __restrict__ twt,
                       const float* __restrict__ nrm, float* __restrict__ out){
    __shared__ float2 C[1728];                   // [u*9 + jj]
    __shared__ float2 A1[1836];                  // [(n2*17+k1)*9 + jj]
    const int DIRI = (DIRSGN > 0) ? 1 : 0;
    int p  = blockIdx.x / NG;
    int g  = blockIdx.x % NG;
    int j0 = g*8;
    int t  = threadIdx.x;                        // 0..383
    float scale = 1.f;
    if (RESCALE){
        int bt = p / NC;
        scale = sqrtf(nrm[bt]) / (sqrtf(nrm[64+bt]) + 1e-6f);
    }
    {   // load: t<192 -> jj 0..3, t>=192 -> jj 4..7
        int u2 = t % 192, hf = t / 192;
        const float2* src = ((const float2*)in) + (long)p*FPIX;
        #pragma unroll
        for (int j2 = 0; j2 < 4; j2++){
            int jj = hf*4 + j2;
            float2 v = {0.f, 0.f};
            if (j0 + jj < WF) v = src[(long)(j0+jj)*HH + u2];
            v.x *= scale; v.y *= scale;
            C[u2*9 + jj] = v;
        }
    }
    __syncthreads();
    int u = t >> 1, h = t & 1;
    const float2* T = twt + DIRI*28*192;
    {   // stage 1
        int n2 = u % 12;
        float wr[8], wi[8];
        #pragma unroll
        for (int n = 0; n < 8; n++){
            float2 w = T[(8*h + n)*192 + u];
            wr[n] = w.x; wi[n] = w.y;
        }
        int k1 = u / 12;
        #pragma unroll
        for (int jj = 0; jj < 8; jj++){
            float re = 0.f, im = 0.f;
            #pragma unroll
            for (int n = 0; n < 8; n++){
                float2 v = C[(12*(8*h + n) + n2)*9 + jj];
                re += v.x*wr[n] - v.y*wi[n];
                im += v.x*wi[n] + v.y*wr[n];
            }
            float reT = re + __shfl_xor(re, 1);
            float imT = im + __shfl_xor(im, 1);
            if (h == 0){
                float2 a; a.x = reT; a.y = imT;
                A1[(n2*17 + k1)*9 + jj] = a;
            }
        }
    }
    __syncthreads();
    {   // stage 2: ky == u
        int kk1 = u % 16;
        float wr[6], wi[6];
        #pragma unroll
        for (int q = 0; q < 6; q++){
            float2 w = T[(16 + 6*h + q)*192 + u];
            wr[q] = w.x; wi[q] = w.y;
        }
        float2* dst = ((float2*)out) + (long)p*FPIX;
        #pragma unroll
        for (int jj = 0; jj < 8; jj++){
            float re = 0.f, im = 0.f;
            #pragma unroll
            for (int q = 0; q < 6; q++){
                float2 a = A1[((6*h + q)*17 + kk1)*9 + jj];
                re += a.x*wr[q] - a.y*wi[q];
                im += a.x*wi[q] + a.y*wr[q];
            }
            float reT = re + __shfl_xor(re, 1);
            float imT = im + __shfl_xor(im, 1);
            if (h == 0 && j0 + jj < WF){
                float2 r; r.x = reT*INV_SQRT_N; r.y = imT*INV_SQRT_N;
                dst[(long)(j0+jj)*HH + u] = r;
            }
        }
    }
}

// ==== scan: 2 complex elements per thread (float4), pre-constrain on load
// ==== (ch0/1), recurrence, post-constrain on store; norms via LDS partials.
__global__ void k_scan(const float* __restrict__ Xf, const float* __restrict__ Abuf,
                       float* __restrict__ Hf, float* __restrict__ scr){
    __shared__ float part[64];                   // [0..31]=in, [32..63]=out
    int tid = threadIdx.x;
    if (tid < 64) part[tid] = 0.f;
    __syncthreads();
    int idx = blockIdx.x*256 + tid;
    int u = idx % HP; int tmp = idx / HP;
    int c = tmp % NC; int b = tmp / NC;
    int f0 = 2*u;
    int lane0 = ((tid & 63) == 0);
    if (c == 0){
        int ky0i = f0 % HH, kxi = f0 / HH;       // f1 = f0+1 shares kx (HH even)
        float ky0 = (float)(ky0i < 96 ? ky0i : ky0i - 192)/192.0f;
        int ky1i = ky0i + 1;
        float ky1 = (float)(ky1i < 96 ? ky1i : ky1i - 192)/192.0f;
        float kx_ = (float)kxi/192.0f;
        float k20 = ky0*ky0 + kx_*kx_; if (f0 == 0) k20 = 1.0f;
        float k21 = ky1*ky1 + kx_*kx_;
        float rk20 = 1.0f/k20, rk21 = 1.0f/k21;
        long a0 = (((long)(b*NC + 0))*FPIX + f0)*2;
        long a1 = (((long)(b*NC + 1))*FPIX + f0)*2;
        float4 A0 = *(const float4*)(Abuf + a0);   // ch0: f0(re,im), f1(re,im)
        float4 A1v = *(const float4*)(Abuf + a1);  // ch1
        float h0r0=0.f,h0i0=0.f,h1r0=0.f,h1i0=0.f; // f0
        float h0r1=0.f,h0i1=0.f,h1r1=0.f,h1i1=0.f; // f1
        for (int t = 0; t < NT; t++){
            long e0 = (((((long)b*NT + t)*NC + 0)*FPIX) + f0)*2;
            long e1 = (((((long)b*NT + t)*NC + 1)*FPIX) + f0)*2;
            float4 U = *(const float4*)(Xf + e0);
            float4 V = *(const float4*)(Xf + e1);
            // --- f0 ---
            float ur = U.x, ui = U.y, vr = V.x, vi = V.y;
            float pr = (ky0*ur + kx_*vr)*rk20;
            float pi = (ky0*ui + kx_*vi)*rk20;
            ur -= ky0*pr; ui -= ky0*pi; vr -= kx_*pr; vi -= kx_*pi;
            float nin = ur*ur + ui*ui + vr*vr + vi*vi;
            float n0r = A0.x*h0r0 - A0.y*h0i0 + ur;
            float n0i = A0.x*h0i0 + A0.y*h0r0 + ui;
            float n1r = A1v.x*h1r0 - A1v.y*h1i0 + vr;
            float n1i = A1v.x*h1i0 + A1v.y*h1r0 + vi;
            h0r0 = n0r; h0i0 = n0i; h1r0 = n1r; h1i0 = n1i;
            float dr = (ky0*h0r0 + kx_*h1r0)*rk20;
            float di = (ky0*h0i0 + kx_*h1i0)*rk20;
            float o0r = h0r0 - ky0*dr, o0i = h0i0 - ky0*di;
            float o1r = h1r0 - kx_*dr, o1i = h1i0 - kx_*di;
            float nout = o0r*o0r + o0i*o0i + o1r*o1r + o1i*o1i;
            // --- f1 ---
            float ur1 = U.z, ui1 = U.w, vr1 = V.z, vi1 = V.w;
            float pr1 = (ky1*ur1 + kx_*vr1)*rk21;
            float pi1 = (ky1*ui1 + kx_*vi1)*rk21;
            ur1 -= ky1*pr1; ui1 -= ky1*pi1; vr1 -= kx_*pr1; vi1 -= kx_*pi1;
            nin += ur1*ur1 + ui1*ui1 + vr1*vr1 + vi1*vi1;
            float m0r = A0.z*h0r1 - A0.w*h0i1 + ur1;
            float m0i = A0.z*h0i1 + A0.w*h0r1 + ui1;
            float m1r = A1v.z*h1r1 - A1v.w*h1i1 + vr1;
            float m1i = A1v.z*h1i1 + A1v.w*h1r1 + vi1;
            h0r1 = m0r; h0i1 = m0i; h1r1 = m1r; h1i1 = m1i;
            float dr1 = (ky1*h0r1 + kx_*h1r1)*rk21;
            float di1 = (ky1*h0i1 + kx_*h1i1)*rk21;
            float q0r = h0r1 - ky1*dr1, q0i = h0i1 - ky1*di1;
            float q1r = h1r1 - kx_*dr1, q1i = h1i1 - kx_*di1;
            nout += q0r*q0r + q0i*q0i + q1r*q1r + q1i*q1i;
            float4 O0; O0.x = o0r; O0.y = o0i; O0.z = q0r; O0.w = q0i;
            float4 O1; O1.x = o1r; O1.y = o1i; O1.z = q1r; O1.w = q1i;
            *(float4*)(Hf + e0) = O0;
            *(float4*)(Hf + e1) = O1;
            #pragma unroll
            for (int off = 32; off > 0; off >>= 1){
                nin  += __shfl_xor(nin,  off);
                nout += __shfl_xor(nout, off);
            }
            if (lane0){
                atomicAdd(&part[t],      nin);   // LDS atomic (per-CU, cheap)
                atomicAdd(&part[32 + t], nout);
            }
        }
    } else if (c != 1){
        long ao = (((long)(b*NC + c))*FPIX + f0)*2;
        float4 A = *(const float4*)(Abuf + ao);
        float hr0 = 0.f, hi0 = 0.f, hr1 = 0.f, hi1 = 0.f;
        for (int t = 0; t < NT; t++){
            long e = (((((long)b*NT + t)*NC + c)*FPIX) + f0)*2;
            float4 X = *(const float4*)(Xf + e);
            float nin = X.x*X.x + X.y*X.y + X.z*X.z + X.w*X.w;
            float nr0 = A.x*hr0 - A.y*hi0 + X.x;
            float ni0 = A.x*hi0 + A.y*hr0 + X.y;
            float nr1 = A.z*hr1 - A.w*hi1 + X.z;
            float ni1 = A.z*hi1 + A.w*hr1 + X.w;
            hr0 = nr0; hi0 = ni0; hr1 = nr1; hi1 = ni1;
            float4 O; O.x = hr0; O.y = hi0; O.z = hr1; O.w = hi1;
            *(float4*)(Hf + e) = O;
            float nout = hr0*hr0 + hi0*hi0 + hr1*hr1 + hi1*hi1;
            #pragma unroll
            for (int off = 32; off > 0; off >>= 1){
                nin  += __shfl_xor(nin,  off);
                nout += __shfl_xor(nout, off);
            }
            if (lane0){
                atomicAdd(&part[t],      nin);
                atomicAdd(&part[32 + t], nout);
            }
        }
    }
    __syncthreads();
    if (tid < 64) scr[(long)blockIdx.x*64 + tid] = part[tid];
}

// ---- reduce scratch partials -> NRM[0..63]=n_in, NRM[64..127]=n_out ----
__global__ void k_nred(const float* __restrict__ scr, float* __restrict__ nrm){
    int o = threadIdx.x;                 // 128 threads
    int io = o >> 6;                     // 0=in, 1=out
    int bt = o & 63;
    int b = bt >> 5, t = bt & 31;
    const int BPB = SCAN_BLOCKS/NB;      // 291 blocks per b
    float s = 0.f;
    for (int blk = 0; blk < BPB; blk++)
        s += scr[((long)(b*BPB + blk))*64 + io*32 + t];
    nrm[io*64 + bt] = s;
}

extern "C" void kernel_launch(void* const* d_in, const int* in_sizes, int n_in,
                              void* d_out, int out_size, void* d_ws, size_t ws_size,
                              hipStream_t stream){
    const float* x   = (const float*)d_in[0];
    const float* dt  = (const float*)d_in[1];
    const float* w1  = (const float*)d_in[2];
    const float* b1  = (const float*)d_in[3];
    const float* w2  = (const float*)d_in[4];
    const float* b2  = (const float*)d_in[5];
    const float* c1w = (const float*)d_in[6];
    const float* c1b = (const float*)d_in[7];
    const float* c2w = (const float*)d_in[8];
    const float* c2b = (const float*)d_in[9];
    const float* c3w = (const float*)d_in[10];
    float* out = (float*)d_out;
    float* ws  = (float*)d_ws;

    const long RSZ = (long)NPLANE*FPIX*2;
    float* R1  = ws;
    float* R2  = ws + RSZ;
    float* AB  = R2 + RSZ;
    float* NRM = AB + (long)NB*NC*FPIX*2;
    float* WTf = NRM + 128;                      // 4608 floats = 9216 bf16
    unsigned short* WT = (unsigned short*)WTf;
    float* S3  = WTf + 4608;                     // 16 floats
    float* SCR = S3 + 16;                        // SCAN_BLOCKS*64 floats
    float2* TWT = (float2*)(SCR + SCAN_BLOCKS*64);  // 10752 float2

    k_twt<<<42, 256, 0, stream>>>(TWT);
    k_wprep<<<37, 256, 0, stream>>>(c1w, c2w, c3w, WT, S3);
    k_A<<<(FPIX + 255)/256, 256, 0, stream>>>(dt, w1, b1, w2, b2, AB);

    k_force_all<<<NBI + NBB, 256, 0, stream>>>(x, WT, c1b, c2b, S3, dt, out);

    k_rowfft2<<<NPLANE*12, 384, 0, stream>>>(out, TWT, R1);
    k_cfft<-1,false><<<NPLANE*NG, 384, 0, stream>>>(R1, TWT, NRM, R2);
    k_scan<<<SCAN_BLOCKS, 256, 0, stream>>>(R2, AB, R1, SCR);
    k_nred<<<1, 128, 0, stream>>>(SCR, NRM);
    k_cfft<+1,true><<<NPLANE*NG, 384, 0, stream>>>(R1, TWT, NRM, R2);
    k_invrow2<<<NPLANE*12, 384, 0, stream>>>(R2, TWT, out);
}

// Round 20
// 522.288 us; speedup vs baseline: 1.0431x; 1.0431x over previous
//
#include <hip/hip_runtime.h>
#include <hip/hip_bf16.h>
#include <math.h>

#define HH 192
#define WW 192
#define WF 97
#define NC 8
#define NC2 16
#define NT 32
#define NB 2
#define NIMG (NB*NT)        // 64
#define NPLANE (NIMG*NC)    // 512
#define PIX (HH*WW)         // 36864
#define FPIX (HH*WF)        // 18624  (layout: [plane][kx][ky], f = kx*192+ky)
#define HP (FPIX/2)         // 9312
#define NG 13               // kx groups of 8 (8*12+1 = 97)
#define INV_SQRT_N 0.07216878364870322f   // 1/sqrt(192)
#define SCAN_BLOCKS (NB*NC*HP/256)        // 582; b never straddles a block
#define NBI (NIMG*100)      // interior force blocks
#define NBB (NIMG*44)       // border force blocks

typedef __attribute__((ext_vector_type(8))) short bf16x8;
typedef __attribute__((ext_vector_type(4))) float f32x4;

__device__ inline unsigned short f2bf(float f){
    union { __hip_bfloat16 h; unsigned short u; } cv;
    cv.h = __float2bfloat16(f);          // HW cvt; compiler packs pairs
    return cv.u;
}
__device__ inline float bf2f(unsigned short h){
    return __uint_as_float(((unsigned int)h) << 16);
}
__device__ inline float fsigmoid(float y){
    return __builtin_amdgcn_rcpf(1.f + __expf(-y));   // 4 VALU instrs
}

// ---- per-thread FFT twiddle table: twt[(dir*28+s)*192 + t] (lane-coalesced)
__global__ void k_twt(float2* __restrict__ twt){
    int e = blockIdx.x*256 + threadIdx.x;        // 2*28*192 = 10752
    if (e >= 10752) return;
    int t = e % 192; int s = (e/192) % 28; int d = e / (192*28);
    int m;
    if (s < 16){ int k1 = t/12, n2 = t%12; m = (n2*k1 + 12*k1*s) % 192; }
    else       { int q = s - 16; int k2 = t/16; m = (16*k2*q) % 192; }
    double ang = 6.283185307179586476925286766559 * (double)m / 192.0;
    float cn = (float)cos(ang), sn = (float)sin(ang);
    float2 w; w.x = cn; w.y = d ? sn : -sn;
    twt[(d*28 + s)*192 + t] = w;
}

// ------- weight fragment table: exact per-lane MFMA A-layout, bf16 -------
__global__ void k_wprep(const float* __restrict__ c1w, const float* __restrict__ c2w,
                        const float* __restrict__ c3w,
                        unsigned short* __restrict__ WT, float* __restrict__ S3){
    int e = blockIdx.x*256 + threadIdx.x;
    if (e < 9216){
        int j  = e & 7;
        int l  = (e >> 3) & 63;
        int fs = e >> 9;
        int px = l & 15, ks = l >> 4;
        float w = 0.f;
        if (fs < 3){                         // ph1: conv1 fwd, K=4taps x 8ch
            int tap = 4*fs + ks;
            if (tap < 9) w = c1w[(px*8 + j)*9 + tap];
        } else if (fs < 8){                  // ph2: conv2 fwd, K=2taps x 16ch
            int s = fs - 3, tap = 2*s + (ks>>1);
            int ch = (ks&1)*8 + j;
            if (tap < 9) w = c2w[(px*16 + ch)*9 + tap];
        } else if (fs < 13){                 // ph3: conv2^T (flipped taps)
            int s = fs - 8, tb = 2*s + (ks>>1);
            int c2 = (ks&1)*8 + j;
            if (tb < 9) w = c2w[(c2*16 + px)*9 + (8 - tb)];
        } else {                             // ph4: conv1^T
            int s = fs - 13, tb = 2*s + (ks>>1);
            int cin = (ks&1)*8 + j;
            if (tb < 9 && px < 8) w = c1w[(cin*8 + px)*9 + (8 - tb)];
        }
        WT[e] = f2bf(w);
    } else if (e < 9232){
        int och = e - 9216;
        float s3 = 0.f;
        for (int q = 0; q < NC; q++) s3 += c3w[q*NC2 + och];
        S3[och] = s3;
    }
}

// ---------------- A = exp(i*omega*dt) via MLP (f = kx*192+ky) ----------------
__global__ void k_A(const float* __restrict__ dt, const float* __restrict__ w1,
                    const float* __restrict__ b1, const float* __restrict__ w2,
                    const float* __restrict__ b2, float* __restrict__ Abuf){
    int idx = blockIdx.x*blockDim.x + threadIdx.x;
    if (idx >= FPIX) return;
    int kyi = idx % HH, kxi = idx / HH;
    float ky = (float)(kyi < 96 ? kyi : kyi - 192) / 192.0f;
    float kx = (float)kxi / 192.0f;
    float lp[NC];
    #pragma unroll
    for (int c = 0; c < NC; c++) lp[c] = b2[c];
    for (int jh = 0; jh < 64; jh++){
        float z  = ky*w1[jh] + kx*w1[64+jh] + b1[jh];
        float sg = __builtin_amdgcn_rcpf(1.0f + __expf(-z));
        float h  = z*sg;
        #pragma unroll
        for (int c = 0; c < NC; c++) lp[c] += h * w2[jh*NC + c];
    }
    float kph = sqrtf(ky*ky + kx*kx);
    for (int b = 0; b < NB; b++){
        float d = dt[b];
        #pragma unroll
        for (int c = 0; c < NC; c++){
            float ph = (lp[c] + kph) * d;
            float s, cn;
            __sincosf(ph, &s, &cn);
            long o = (((long)(b*NC + c))*FPIX + idx) * 2;
            Abuf[o]   = cn;
            Abuf[o+1] = s;
        }
    }
}

// ============ FUSED force chain body (interior/border specialized) ========
template<int BORDER>
__device__ __forceinline__ void force_body(
        int img, int tx0, int ty0,
        const float* __restrict__ x, const bf16x8* __restrict__ wt,
        const float* __restrict__ c1b, const float* __restrict__ c2b,
        const float* __restrict__ S3,  const float* __restrict__ dt,
        float* __restrict__ xp,
        unsigned short* ys1_s, unsigned short* xg2_s){
    int tid = threadIdx.x;
    int l = tid & 63, px = l & 15, ks = l >> 4, wv = tid >> 6;

    // ---- stage x: 24x24 halo, 8ch ch-last bf16 ----
    unsigned short* xs = xg2_s;                  // [pix*8 + c]
    const float* xb = x + (long)img*NC*PIX;
    for (int pix = tid; pix < 576; pix += 256){
        int sy = pix / 24, sx = pix % 24;
        int gy = ty0 - 4 + sy, gx = tx0 - 4 + sx;
        bool vld = true;
        if constexpr (BORDER != 0)
            vld = (gy >= 0 && gy < HH && gx >= 0 && gx < WW);
        long gp = (long)gy*WW + gx;
        ushort4 o0, o1;
        #pragma unroll
        for (int c = 0; c < 8; c++){
            float v = vld ? xb[c*PIX + gp] : 0.f;
            unsigned short h = f2bf(v);
            if (c < 4) ((unsigned short*)&o0)[c] = h;
            else       ((unsigned short*)&o1)[c-4] = h;
        }
        *(ushort4*)(xs + pix*8)     = o0;
        *(ushort4*)(xs + pix*8 + 4) = o1;
    }
    __syncthreads();

    ushort4 dy1r[6];                             // dy1 inner tile, in regs
    // ---- phase 1: conv1 -> ys1 (22x22x16), dy1 (18x18) in registers ----
    {
        bf16x8 a0 = wt[0*64 + l], a1 = wt[1*64 + l], a2 = wt[2*64 + l];
        float b1v[4];
        #pragma unroll
        for (int r = 0; r < 4; r++) b1v[r] = c1b[ks*4 + r];
        int t0 = (0 + ks < 9) ? ks : 8;          // taps for s=0,1,2
        int t1 = (4 + ks < 9) ? 4 + ks : 8;
        int t2 = 8;
        int o0 = ((t0/3)*24 + t0%3)*8, o1 = ((t1/3)*24 + t1%3)*8, o2 = ((t2/3)*24 + t2%3)*8;
        // pass A: inner 324 pixels (18x18), SAME p-mapping as phase 3
        #pragma unroll
        for (int i = 0; i < 6; i++){
            int g = wv + 4*i;
            if (g < 21){
                int p = g*16 + px;
                int pc = (p < 324) ? p : 323;
                int ry = pc/18, rx = pc%18;
                const unsigned short* bp = xs + ((ry+2)*24 + rx+2)*8;
                f32x4 acc = {0.f,0.f,0.f,0.f};
                acc = __builtin_amdgcn_mfma_f32_16x16x32_bf16(a0, *(const bf16x8*)(bp+o0), acc, 0,0,0);
                acc = __builtin_amdgcn_mfma_f32_16x16x32_bf16(a1, *(const bf16x8*)(bp+o1), acc, 0,0,0);
                acc = __builtin_amdgcn_mfma_f32_16x16x32_bf16(a2, *(const bf16x8*)(bp+o2), acc, 0,0,0);
                bool vld = true;
                if constexpr (BORDER != 0){
                    int gy = ty0 - 1 + ry, gx = tx0 - 1 + rx;
                    vld = (gy >= 0 && gy < HH && gx >= 0 && gx < WW);
                }
                ushort4 yo, dyo;
                #pragma unroll
                for (int r = 0; r < 4; r++){
                    float yv = acc[r] + b1v[r];
                    float sg = fsigmoid(yv);
                    ((unsigned short*)&yo)[r]  = vld ? f2bf(yv*sg) : (unsigned short)0;
                    ((unsigned short*)&dyo)[r] = vld ? f2bf(sg*(1.f + yv*(1.f - sg)))
                                                     : (unsigned short)0;
                }
                dy1r[i] = dyo;
                if (p < 324)
                    *(ushort4*)(ys1_s + ((ry+2)*22 + rx+2)*16 + ks*4) = yo;
            }
        }
        // pass B: ring 160 pixels of the 22x22 ys1 tile (no dy1 needed)
        #pragma unroll
        for (int i = 0; i < 3; i++){
            int g = wv + 4*i;
            if (g < 10){
                int p = g*16 + px;               // 0..159
                int oy, ox;
                if (p < 88){ int q = p/22; oy = (q < 2) ? q : q + 18; ox = p - q*22; }
                else { int rr = p - 88; oy = (rr>>2) + 2; int c4 = rr & 3;
                       ox = (c4 < 2) ? c4 : c4 + 18; }
                const unsigned short* bp = xs + (oy*24 + ox)*8;
                f32x4 acc = {0.f,0.f,0.f,0.f};
                acc = __builtin_amdgcn_mfma_f32_16x16x32_bf16(a0, *(const bf16x8*)(bp+o0), acc, 0,0,0);
                acc = __builtin_amdgcn_mfma_f32_16x16x32_bf16(a1, *(const bf16x8*)(bp+o1), acc, 0,0,0);
                acc = __builtin_amdgcn_mfma_f32_16x16x32_bf16(a2, *(const bf16x8*)(bp+o2), acc, 0,0,0);
                bool vld = true;
                if constexpr (BORDER != 0){
                    int gy = ty0 - 3 + oy, gx = tx0 - 3 + ox;
                    vld = (gy >= 0 && gy < HH && gx >= 0 && gx < WW);
                }
                ushort4 yo;
                #pragma unroll
                for (int r = 0; r < 4; r++){
                    float yv = acc[r] + b1v[r];
                    float sg = fsigmoid(yv);
                    ((unsigned short*)&yo)[r] = vld ? f2bf(yv*sg) : (unsigned short)0;
                }
                *(ushort4*)(ys1_s + (oy*22 + ox)*16 + ks*4) = yo;
            }
        }
    }
    __syncthreads();

    // ---- phase 2: conv2 -> g2 (20x20x16) over dead xs ----
    unsigned short* g2s = xg2_s;
    {
        bf16x8 a0 = wt[3*64+l], a1 = wt[4*64+l], a2 = wt[5*64+l],
               a3 = wt[6*64+l], a4 = wt[7*64+l];
        float b2v[4], s3v[4];
        #pragma unroll
        for (int r = 0; r < 4; r++){ b2v[r] = c2b[ks*4+r]; s3v[r] = S3[ks*4+r]; }
        int hb = (ks&1)*8;
        int toff[5];
        #pragma unroll
        for (int s = 0; s < 5; s++){
            int tap = 2*s + (ks>>1); int t = (tap < 9) ? tap : 8;
            toff[s] = ((t/3)*22 + t%3)*16 + hb;
        }
        #pragma unroll
        for (int i = 0; i < 7; i++){
            int g = wv + 4*i;
            if (g < 25){
                int p = g*16 + px;               // < 400 always
                int qy = p/20, qx = p%20;
                const unsigned short* bp = ys1_s + (qy*22 + qx)*16;
                f32x4 acc = {0.f,0.f,0.f,0.f};
                acc = __builtin_amdgcn_mfma_f32_16x16x32_bf16(a0, *(const bf16x8*)(bp+toff[0]), acc, 0,0,0);
                acc = __builtin_amdgcn_mfma_f32_16x16x32_bf16(a1, *(const bf16x8*)(bp+toff[1]), acc, 0,0,0);
                acc = __builtin_amdgcn_mfma_f32_16x16x32_bf16(a2, *(const bf16x8*)(bp+toff[2]), acc, 0,0,0);
                acc = __builtin_amdgcn_mfma_f32_16x16x32_bf16(a3, *(const bf16x8*)(bp+toff[3]), acc, 0,0,0);
                acc = __builtin_amdgcn_mfma_f32_16x16x32_bf16(a4, *(const bf16x8*)(bp+toff[4]), acc, 0,0,0);
                bool vld = true;
                if constexpr (BORDER != 0){
                    int gy = ty0 - 2 + qy, gx = tx0 - 2 + qx;
                    vld = (gy >= 0 && gy < HH && gx >= 0 && gx < WW);
                }
                ushort4 go;
                #pragma unroll
                for (int r = 0; r < 4; r++){
                    float yv = acc[r] + b2v[r];
                    float sg = fsigmoid(yv);
                    float ds = sg*(1.f + yv*(1.f - sg));
                    ((unsigned short*)&go)[r] = vld ? f2bf(ds * s3v[r]) : (unsigned short)0;
                }
                *(ushort4*)(g2s + p*16 + ks*4) = go;
            }
        }
    }
    __syncthreads();

    // ---- phase 3: g1 = dy1r * conv2^T(g2) (18x18x16) over dead ys1 ----
    unsigned short* g1s = ys1_s;
    {
        bf16x8 a0 = wt[8*64+l], a1 = wt[9*64+l], a2 = wt[10*64+l],
               a3 = wt[11*64+l], a4 = wt[12*64+l];
        int hb = (ks&1)*8;
        int toff[5];
        #pragma unroll
        for (int s = 0; s < 5; s++){
            int tb = 2*s + (ks>>1); int t = (tb < 9) ? tb : 8;
            toff[s] = ((2-(t/3))*20 + 2-(t%3))*16 + hb;   // flipped taps
        }
        #pragma unroll
        for (int i = 0; i < 6; i++){
            int g = wv + 4*i;
            if (g < 21){
                int p = g*16 + px;
                int pc = (p < 324) ? p : 323;
                int ry = pc/18, rx = pc%18;
                const unsigned short* bp = g2s + (ry*20 + rx)*16;
                f32x4 acc = {0.f,0.f,0.f,0.f};
                acc = __builtin_amdgcn_mfma_f32_16x16x32_bf16(a0, *(const bf16x8*)(bp+toff[0]), acc, 0,0,0);
                acc = __builtin_amdgcn_mfma_f32_16x16x32_bf16(a1, *(const bf16x8*)(bp+toff[1]), acc, 0,0,0);
                acc = __builtin_amdgcn_mfma_f32_16x16x32_bf16(a2, *(const bf16x8*)(bp+toff[2]), acc, 0,0,0);
                acc = __builtin_amdgcn_mfma_f32_16x16x32_bf16(a3, *(const bf16x8*)(bp+toff[3]), acc, 0,0,0);
                acc = __builtin_amdgcn_mfma_f32_16x16x32_bf16(a4, *(const bf16x8*)(bp+toff[4]), acc, 0,0,0);
                if (p < 324){
                    ushort4 dv = dy1r[i];
                    ushort4 go;
                    #pragma unroll
                    for (int r = 0; r < 4; r++){
                        float v = acc[r] * bf2f(((unsigned short*)&dv)[r]);
                        ((unsigned short*)&go)[r] = f2bf(v);
                    }
                    *(ushort4*)(g1s + p*16 + ks*4) = go;
                }
            }
        }
    }
    __syncthreads();

    // ---- phase 4: xp = x + dt * conv1^T(g1), 16x16, 8 out-ch ----
    {
        bf16x8 a0 = wt[13*64+l], a1 = wt[14*64+l], a2 = wt[15*64+l],
               a3 = wt[16*64+l], a4 = wt[17*64+l];
        int hb = (ks&1)*8;
        int toff[5];
        #pragma unroll
        for (int s = 0; s < 5; s++){
            int tb = 2*s + (ks>>1); int t = (tb < 9) ? tb : 8;
            toff[s] = ((2-(t/3))*18 + 2-(t%3))*16 + hb;
        }
        float d = dt[img / NT];
        #pragma unroll
        for (int i = 0; i < 4; i++){
            int y = wv + 4*i;
            const unsigned short* bp = g1s + (y*18 + px)*16;
            f32x4 acc = {0.f,0.f,0.f,0.f};
            acc = __builtin_amdgcn_mfma_f32_16x16x32_bf16(a0, *(const bf16x8*)(bp+toff[0]), acc, 0,0,0);
            acc = __builtin_amdgcn_mfma_f32_16x16x32_bf16(a1, *(const bf16x8*)(bp+toff[1]), acc, 0,0,0);
            acc = __builtin_amdgcn_mfma_f32_16x16x32_bf16(a2, *(const bf16x8*)(bp+toff[2]), acc, 0,0,0);
            acc = __builtin_amdgcn_mfma_f32_16x16x32_bf16(a3, *(const bf16x8*)(bp+toff[3]), acc, 0,0,0);
            acc = __builtin_amdgcn_mfma_f32_16x16x32_bf16(a4, *(const bf16x8*)(bp+toff[4]), acc, 0,0,0);
            if (ks < 2){
                int gpix = (ty0+y)*WW + (tx0+px);
                #pragma unroll
                for (int r = 0; r < 4; r++){
                    int c = ks*4 + r;
                    long gi = ((long)img*NC + c)*PIX + gpix;
                    xp[gi] = x[gi] + d*acc[r];
                }
            }
        }
    }
}

// single launch: interior blocks [0, NBI), border blocks [NBI, NBI+NBB)
__global__ void __launch_bounds__(256) k_force_all(
        const float* __restrict__ x, const unsigned short* __restrict__ WTu,
        const float* __restrict__ c1b, const float* __restrict__ c2b,
        const float* __restrict__ S3,  const float* __restrict__ dt,
        float* __restrict__ xp){
    __shared__ unsigned short ys1_s[22*22*16];   // later g1 (18x18x16)
    __shared__ unsigned short xg2_s[20*20*16];   // xs (24x24x8) then g2
    const bf16x8* wt = (const bf16x8*)WTu;
    int bid = blockIdx.x;
    if (bid < NBI){
        int img = bid / 100; int t10 = bid % 100;
        int ty0 = (1 + t10/10)*16, tx0 = (1 + t10%10)*16;
        force_body<0>(img, tx0, ty0, x, wt, c1b, c2b, S3, dt, xp, ys1_s, xg2_s);
    } else {
        int e0 = bid - NBI;
        int img = e0 / 44; int e = e0 % 44;
        int r, c;
        if (e < 12){ r = 0; c = e; }
        else if (e < 24){ r = 11; c = e - 12; }
        else if (e < 34){ r = e - 23; c = 0; }
        else { r = e - 33; c = 11; }
        force_body<1>(img, c*16, r*16, x, wt, c1b, c2b, S3, dt, xp, ys1_s, xg2_s);
    }
}

// ====== row rfft (192=16x12), 2 real rows per complex; 16 rows/block =======
// (16-row tiling is load-bearing: full 128B-line global writes — r14 lesson;
//  192 threads is load-bearing: r19's 2-thread split regressed)
__global__ void k_rowfft2(const float* __restrict__ xp, const float2* __restrict__ twt,
                          float* __restrict__ R){
    __shared__ float2 bufC[1728];
    __shared__ float2 bufA[1836];
    int p  = blockIdx.x / 12;
    int r0 = (blockIdx.x % 12)*16;
    int t  = threadIdx.x;
    const float* base = xp + (long)p*PIX + (long)r0*WW;
    #pragma unroll
    for (int jj = 0; jj < 8; jj++){
        float2 z; z.x = base[(2*jj)*WW + t]; z.y = base[(2*jj+1)*WW + t];
        bufC[t*9 + jj] = z;
    }
    __syncthreads();
    int k1 = t / 12, n2 = t % 12;
    {   // stage 1 (fwd, dir 0)
        float wr[16], wi[16];
        #pragma unroll
        for (int n1 = 0; n1 < 16; n1++){
            float2 w = twt[n1*192 + t];
            wr[n1] = w.x; wi[n1] = w.y;
        }
        #pragma unroll
        for (int jj = 0; jj < 8; jj++){
            float re = 0.f, im = 0.f;
            #pragma unroll
            for (int n1 = 0; n1 < 16; n1++){
                float2 v = bufC[(12*n1 + n2)*9 + jj];
                re += v.x*wr[n1] - v.y*wi[n1];
                im += v.x*wi[n1] + v.y*wr[n1];
            }
            float2 a; a.x = re; a.y = im;
            bufA[(n2*17 + k1)*9 + jj] = a;
        }
    }
    __syncthreads();
    {   // stage 2
        int kk1 = t % 16;
        float wr[12], wi[12];
        #pragma unroll
        for (int q = 0; q < 12; q++){
            float2 w = twt[(16+q)*192 + t];
            wr[q] = w.x; wi[q] = w.y;
        }
        #pragma unroll
        for (int jj = 0; jj < 8; jj++){
            float re = 0.f, im = 0.f;
            #pragma unroll
            for (int q = 0; q < 12; q++){
                float2 a = bufA[(q*17 + kk1)*9 + jj];
                re += a.x*wr[q] - a.y*wi[q];
                im += a.x*wi[q] + a.y*wr[q];
            }
            float2 z; z.x = re*INV_SQRT_N; z.y = im*INV_SQRT_N;
            bufC[t*9 + jj] = z;
        }
    }
    __syncthreads();
    if (t < WF){   // Hermitian unpack -> U (overlaid on bufA)
        int t2 = (t == 0) ? 0 : 192 - t;
        #pragma unroll
        for (int jj = 0; jj < 8; jj++){
            float2 u = bufC[t*9 + jj], v = bufC[t2*9 + jj];
            float2 A_; A_.x = 0.5f*(u.x + v.x); A_.y = 0.5f*(u.y - v.y);
            float2 B_; B_.x = 0.5f*(u.y + v.y); B_.y = -0.5f*(u.x - v.x);
            bufA[t*17 + 2*jj]     = A_;
            bufA[t*17 + 2*jj + 1] = B_;
        }
    }
    __syncthreads();
    float2* dst = ((float2*)R) + (long)p*FPIX + r0;
    for (int idx = t; idx < 97*16; idx += 192){
        int kx = idx >> 4, ry = idx & 15;
        dst[(long)kx*HH + ry] = bufA[kx*17 + ry];
    }
}

// ====== inverse row irfft, in [plane][kx][ky]; 2 spectra per complex ifft ==
// C2R: Im of DC (kx=0) and Nyquist (kx=96) bins zeroed (numpy convention).
__global__ void k_invrow2(const float* __restrict__ G, const float2* __restrict__ twt,
                          float* __restrict__ out){
    __shared__ float2 bufC[1728];
    __shared__ float2 bufA[1836];
    int p  = blockIdx.x / 12;
    int r0 = (blockIdx.x % 12)*16;
    int t  = threadIdx.x;
    const float2* Gb = ((const float2*)G) + (long)p*FPIX + r0;
    for (int idx = t; idx < 97*16; idx += 192){
        int kx = idx >> 4, ry = idx & 15;
        bufA[kx*17 + ry] = Gb[(long)kx*HH + ry];
    }
    __syncthreads();
    int tt = (t <= 96) ? t : 192 - t;
    bool dcny = (t == 0) || (t == 96);
    #pragma unroll
    for (int jj = 0; jj < 8; jj++){
        float2 a = bufA[tt*17 + 2*jj];
        float2 b = bufA[tt*17 + 2*jj + 1];
        if (dcny){ a.y = 0.f; b.y = 0.f; }
        float2 z;
        if (t <= 96){ z.x = a.x - b.y; z.y = a.y + b.x; }
        else        { z.x = a.x + b.y; z.y = b.x - a.y; }
        bufC[t*9 + jj] = z;
    }
    __syncthreads();
    int k1 = t / 12, n2 = t % 12;
    const float2* T = twt + 28*192;              // dir 1 (inverse)
    {   // stage 1 (e^{+i})
        float wr[16], wi[16];
        #pragma unroll
        for (int n1 = 0; n1 < 16; n1++){
            float2 w = T[n1*192 + t];
            wr[n1] = w.x; wi[n1] = w.y;
        }
        #pragma unroll
        for (int jj = 0; jj < 8; jj++){
            float re = 0.f, im = 0.f;
            #pragma unroll
            for (int n1 = 0; n1 < 16; n1++){
                float2 v = bufC[(12*n1 + n2)*9 + jj];
                re += v.x*wr[n1] - v.y*wi[n1];
                im += v.x*wi[n1] + v.y*wr[n1];
            }
            float2 a; a.x = re; a.y = im;
            bufA[(n2*17 + k1)*9 + jj] = a;
        }
    }
    __syncthreads();
    {   // stage 2 (e^{+i})
        int kk1 = t % 16;
        float wr[12], wi[12];
        #pragma unroll
        for (int q = 0; q < 12; q++){
            float2 w = T[(16+q)*192 + t];
            wr[q] = w.x; wi[q] = w.y;
        }
        float* ob = out + (long)p*PIX + (long)r0*WW;
        #pragma unroll
        for (int jj = 0; jj < 8; jj++){
            float re = 0.f, im = 0.f;
            #pragma unroll
            for (int q = 0; q < 12; q++){
                float2 a = bufA[(q*17 + kk1)*9 + jj];
                re += a.x*wr[q] - a.y*wi[q];
                im += a.x*wi[q] + a.y*wr[q];
            }
            ob[(2*jj)*WW + t]   = re*INV_SQRT_N;
            ob[(2*jj+1)*WW + t] = im*INV_SQRT_N;
        }
    }
}

// ========== column FFT on [plane][kx][ky] (monolithic, proven) ======
template<int DIRSGN, bool RESCALE>
__global__ void k_cfft(const float* __restrict__ in, const float2* __restrict__ twt,
                       const float* __restrict__ nrm, float* __restrict__ out){
    __shared__ float2 C[HH][9];
    __shared__ float2 A1[12][17][9];
    const int DIRI = (DIRSGN > 0) ? 1 : 0;
    int p  = blockIdx.x / NG;
    int g  = blockIdx.x % NG;
    int j0 = g*8;
    int t  = threadIdx.x;
    float scale = 1.f;
    if (RESCALE){
        int bt = p / NC;
        scale = sqrtf(nrm[bt]) / (sqrtf(nrm[64+bt]) + 1e-6f);
    }
    const float2* src = ((const float2*)in) + (long)p*FPIX;
    #pragma unroll
    for (int jj = 0; jj < 8; jj++){
        float2 v = {0.f, 0.f};
        if (j0 + jj < WF) v = src[(long)(j0+jj)*HH + t];
        v.x *= scale; v.y *= scale;
        C[t][jj] = v;
    }
    __syncthreads();
    const float2* T = twt + DIRI*28*192;
    {   // stage 1
        int k1 = t / 12, n2 = t % 12;
        float wr[16], wi[16];
        #pragma unroll
        for (int n1 = 0; n1 < 16; n1++){
            float2 w = T[n1*192 + t];
            wr[n1] = w.x; wi[n1] = w.y;
        }
        #pragma unroll
        for (int jj = 0; jj < 8; jj++){
            float re = 0.f, im = 0.f;
            #pragma unroll
            for (int n1 = 0; n1 < 16; n1++){
                float2 v = C[12*n1 + n2][jj];
                re += v.x*wr[n1] - v.y*wi[n1];
                im += v.x*wi[n1] + v.y*wr[n1];
            }
            float2 a; a.x = re; a.y = im;
            A1[n2][k1][jj] = a;
        }
    }
    __syncthreads();
    {   // stage 2: ky == t
        int k1 = t % 16;
        float wr[12], wi[12];
        #pragma unroll
        for (int q = 0; q < 12; q++){
            float2 w = T[(16+q)*192 + t];
            wr[q] = w.x; wi[q] = w.y;
        }
        float2* dst = ((float2*)out) + (long)p*FPIX;
        #pragma unroll
        for (int jj = 0; jj < 8; jj++){
            float re = 0.f, im = 0.f;
            #pragma unroll
            for (int q = 0; q < 12; q++){
                float2 a = A1[q][k1][jj];
                re += a.x*wr[q] - a.y*wi[q];
                im += a.x*wi[q] + a.y*wr[q];
            }
            if (j0 + jj < WF){
                float2 r; r.x = re*INV_SQRT_N; r.y = im*INV_SQRT_N;
                dst[(long)(j0+jj)*HH + t] = r;
            }
        }
    }
}

// ==== scan: 2 complex elements per thread (float4), pre-constrain on load
// ==== (ch0/1), recurrence, post-constrain on store; norms via LDS partials.
__global__ void k_scan(const float* __restrict__ Xf, const float* __restrict__ Abuf,
                       float* __restrict__ Hf, float* __restrict__ scr){
    __shared__ float part[64];                   // [0..31]=in, [32..63]=out
    int tid = threadIdx.x;
    if (tid < 64) part[tid] = 0.f;
    __syncthreads();
    int idx = blockIdx.x*256 + tid;
    int u = idx % HP; int tmp = idx / HP;
    int c = tmp % NC; int b = tmp / NC;
    int f0 = 2*u;
    int lane0 = ((tid & 63) == 0);
    if (c == 0){
        int ky0i = f0 % HH, kxi = f0 / HH;       // f1 = f0+1 shares kx (HH even)
        float ky0 = (float)(ky0i < 96 ? ky0i : ky0i - 192)/192.0f;
        int ky1i = ky0i + 1;
        float ky1 = (float)(ky1i < 96 ? ky1i : ky1i - 192)/192.0f;
        float kx_ = (float)kxi/192.0f;
        float k20 = ky0*ky0 + kx_*kx_; if (f0 == 0) k20 = 1.0f;
        float k21 = ky1*ky1 + kx_*kx_;
        float rk20 = 1.0f/k20, rk21 = 1.0f/k21;
        long a0 = (((long)(b*NC + 0))*FPIX + f0)*2;
        long a1 = (((long)(b*NC + 1))*FPIX + f0)*2;
        float4 A0 = *(const float4*)(Abuf + a0);   // ch0: f0(re,im), f1(re,im)
        float4 A1v = *(const float4*)(Abuf + a1);  // ch1
        float h0r0=0.f,h0i0=0.f,h1r0=0.f,h1i0=0.f; // f0
        float h0r1=0.f,h0i1=0.f,h1r1=0.f,h1i1=0.f; // f1
        for (int t = 0; t < NT; t++){
            long e0 = (((((long)b*NT + t)*NC + 0)*FPIX) + f0)*2;
            long e1 = (((((long)b*NT + t)*NC + 1)*FPIX) + f0)*2;
            float4 U = *(const float4*)(Xf + e0);
            float4 V = *(const float4*)(Xf + e1);
            // --- f0 ---
            float ur = U.x, ui = U.y, vr = V.x, vi = V.y;
            float pr = (ky0*ur + kx_*vr)*rk20;
            float pi = (ky0*ui + kx_*vi)*rk20;
            ur -= ky0*pr; ui -= ky0*pi; vr -= kx_*pr; vi -= kx_*pi;
            float nin = ur*ur + ui*ui + vr*vr + vi*vi;
            float n0r = A0.x*h0r0 - A0.y*h0i0 + ur;
            float n0i = A0.x*h0i0 + A0.y*h0r0 + ui;
            float n1r = A1v.x*h1r0 - A1v.y*h1i0 + vr;
            float n1i = A1v.x*h1i0 + A1v.y*h1r0 + vi;
            h0r0 = n0r; h0i0 = n0i; h1r0 = n1r; h1i0 = n1i;
            float dr = (ky0*h0r0 + kx_*h1r0)*rk20;
            float di = (ky0*h0i0 + kx_*h1i0)*rk20;
            float o0r = h0r0 - ky0*dr, o0i = h0i0 - ky0*di;
            float o1r = h1r0 - kx_*dr, o1i = h1i0 - kx_*di;
            float nout = o0r*o0r + o0i*o0i + o1r*o1r + o1i*o1i;
            // --- f1 ---
            float ur1 = U.z, ui1 = U.w, vr1 = V.z, vi1 = V.w;
            float pr1 = (ky1*ur1 + kx_*vr1)*rk21;
            float pi1 = (ky1*ui1 + kx_*vi1)*rk21;
            ur1 -= ky1*pr1; ui1 -= ky1*pi1; vr1 -= kx_*pr1; vi1 -= kx_*pi1;
            nin += ur1*ur1 + ui1*ui1 + vr1*vr1 + vi1*vi1;
            float m0r = A0.z*h0r1 - A0.w*h0i1 + ur1;
            float m0i = A0.z*h0i1 + A0.w*h0r1 + ui1;
            float m1r = A1v.z*h1r1 - A1v.w*h1i1 + vr1;
            float m1i = A1v.z*h1i1 + A1v.w*h1r1 + vi1;
            h0r1 = m0r; h0i1 = m0i; h1r1 = m1r; h1i1 = m1i;
            float dr1 = (ky1*h0r1 + kx_*h1r1)*rk21;
            float di1 = (ky1*h0i1 + kx_*h1i1)*rk21;
            float q0r = h0r1 - ky1*dr1, q0i = h0i1 - ky1*di1;
            float q1r = h1r1 - kx_*dr1, q1i = h1i1 - kx_*di1;
            nout += q0r*q0r + q0i*q0i + q1r*q1r + q1i*q1i;
            float4 O0; O0.x = o0r; O0.y = o0i; O0.z = q0r; O0.w = q0i;
            float4 O1; O1.x = o1r; O1.y = o1i; O1.z = q1r; O1.w = q1i;
            *(float4*)(Hf + e0) = O0;
            *(float4*)(Hf + e1) = O1;
            #pragma unroll
            for (int off = 32; off > 0; off >>= 1){
                nin  += __shfl_xor(nin,  off);
                nout += __shfl_xor(nout, off);
            }
            if (lane0){
                atomicAdd(&part[t],      nin);   // LDS atomic (per-CU, cheap)
                atomicAdd(&part[32 + t], nout);
            }
        }
    } else if (c != 1){
        long ao = (((long)(b*NC + c))*FPIX + f0)*2;
        float4 A = *(const float4*)(Abuf + ao);
        float hr0 = 0.f, hi0 = 0.f, hr1 = 0.f, hi1 = 0.f;
        for (int t = 0; t < NT; t++){
            long e = (((((long)b*NT + t)*NC + c)*FPIX) + f0)*2;
            float4 X = *(const float4*)(Xf + e);
            float nin = X.x*X.x + X.y*X.y + X.z*X.z + X.w*X.w;
            float nr0 = A.x*hr0 - A.y*hi0 + X.x;
            float ni0 = A.x*hi0 + A.y*hr0 + X.y;
            float nr1 = A.z*hr1 - A.w*hi1 + X.z;
            float ni1 = A.z*hi1 + A.w*hr1 + X.w;
            hr0 = nr0; hi0 = ni0; hr1 = nr1; hi1 = ni1;
            float4 O; O.x = hr0; O.y = hi0; O.z = hr1; O.w = hi1;
            *(float4*)(Hf + e) = O;
            float nout = hr0*hr0 + hi0*hi0 + hr1*hr1 + hi1*hi1;
            #pragma unroll
            for (int off = 32; off > 0; off >>= 1){
                nin  += __shfl_xor(nin,  off);
                nout += __shfl_xor(nout, off);
            }
            if (lane0){
                atomicAdd(&part[t],      nin);
                atomicAdd(&part[32 + t], nout);
            }
        }
    }
    __syncthreads();
    if (tid < 64) scr[(long)blockIdx.x*64 + tid] = part[tid];
}

// ---- reduce scratch partials -> NRM[0..63]=n_in, NRM[64..127]=n_out ----
__global__ void k_nred(const float* __restrict__ scr, float* __restrict__ nrm){
    int o = threadIdx.x;                 // 128 threads
    int io = o >> 6;                     // 0=in, 1=out
    int bt = o & 63;
    int b = bt >> 5, t = bt & 31;
    const int BPB = SCAN_BLOCKS/NB;      // 291 blocks per b
    float s = 0.f;
    for (int blk = 0; blk < BPB; blk++)
        s += scr[((long)(b*BPB + blk))*64 + io*32 + t];
    nrm[io*64 + bt] = s;
}

extern "C" void kernel_launch(void* const* d_in, const int* in_sizes, int n_in,
                              void* d_out, int out_size, void* d_ws, size_t ws_size,
                              hipStream_t stream){
    const float* x   = (const float*)d_in[0];
    const float* dt  = (const float*)d_in[1];
    const float* w1  = (const float*)d_in[2];
    const float* b1  = (const float*)d_in[3];
    const float* w2  = (const float*)d_in[4];
    const float* b2  = (const float*)d_in[5];
    const float* c1w = (const float*)d_in[6];
    const float* c1b = (const float*)d_in[7];
    const float* c2w = (const float*)d_in[8];
    const float* c2b = (const float*)d_in[9];
    const float* c3w = (const float*)d_in[10];
    float* out = (float*)d_out;
    float* ws  = (float*)d_ws;

    const long RSZ = (long)NPLANE*FPIX*2;
    float* R1  = ws;
    float* R2  = ws + RSZ;
    float* AB  = R2 + RSZ;
    float* NRM = AB + (long)NB*NC*FPIX*2;
    float* WTf = NRM + 128;                      // 4608 floats = 9216 bf16
    unsigned short* WT = (unsigned short*)WTf;
    float* S3  = WTf + 4608;                     // 16 floats
    float* SCR = S3 + 16;                        // SCAN_BLOCKS*64 floats
    float2* TWT = (float2*)(SCR + SCAN_BLOCKS*64);  // 10752 float2

    k_twt<<<42, 256, 0, stream>>>(TWT);
    k_wprep<<<37, 256, 0, stream>>>(c1w, c2w, c3w, WT, S3);
    k_A<<<(FPIX + 255)/256, 256, 0, stream>>>(dt, w1, b1, w2, b2, AB);

    k_force_all<<<NBI + NBB, 256, 0, stream>>>(x, WT, c1b, c2b, S3, dt, out);

    k_rowfft2<<<NPLANE*12, 192, 0, stream>>>(out, TWT, R1);
    k_cfft<-1,false><<<NPLANE*NG, 192, 0, stream>>>(R1, TWT, NRM, R2);
    k_scan<<<SCAN_BLOCKS, 256, 0, stream>>>(R2, AB, R1, SCR);
    k_nred<<<1, 128, 0, stream>>>(SCR, NRM);
    k_cfft<+1,true><<<NPLANE*NG, 192, 0, stream>>>(R1, TWT, NRM, R2);
    k_invrow2<<<NPLANE*12, 192, 0, stream>>>(R2, TWT, out);
}